// Round 12
// baseline (309.612 us; speedup 1.0000x reference)
//
#include <hip/hip_runtime.h>

// Orient_Conv: 3x3 orientation-gated conv, 4 orientations + per-pixel argmax.
// B=4, CIN=COUT=32, H=W=128, pad=1.
//
// Gate identity (C=cos(wr), S=sin(wr), r0=cos(th), r1=sin(th)):
//   u = C*r0+S*r1, vv = C*r1-S*r0
//   gates: o0=relu(u), o1=relu(vv), o2=relu(-u), o3=relu(-vv)
//   products: t0=f*relu(u), t1=f*relu(vv), t2=t0-f*u, t3=t1-f*vv
//   -> 14-slot core/elem (VALU-slot floor ~108 us; v_pk = 2 slots, no width).
// Rotated weights at tap (i,j): w0=w[i][j], w1=w[2-j][i], w2=w[2-i][2-j],
//   w3=w[j][2-i].
//
// R11 = R10 (239 us) minus splats minus barriers:
//  - weight table pre-duplicated [cc][tap][oc][12] = {C,C,S,S,w0,w0,w1,w1,
//    w2,w2,w3,w3}: 3 b128 loads/tap, float4 pairs alias directly to v2f
//    operands (zero splat movs; was 6 movs/tap = ~12 us busy).
//  - NC=16: 2 staging groups, 4 barriers total (was 8) -> convoy idle halved.
// Interleaved-pair LDS ({col,col+32}), R5 register prefetch, 512-thr block.

typedef float v2f __attribute__((ext_vector_type(2)));

#define B_    4
#define CIN_  32
#define COUT_ 32
#define H_    128
#define W_    128
#define HW_   (H_ * W_)
#define OUTSZ_ (B_ * COUT_ * H_ * W_)

// tab: [cc][tap][oc][12]; 9216 * 48 B = 442368 B
__global__ __launch_bounds__(256)
void build_wtab(const float* __restrict__ w, const float* __restrict__ wr,
                float* __restrict__ tab)
{
    int idx = blockIdx.x * 256 + threadIdx.x;   // ((cc*9+tap)<<5)|oc
    if (idx >= CIN_ * 9 * COUT_) return;        // 9216
    int oc  = idx & 31;
    int t2  = idx >> 5;
    int tap = t2 % 9;
    int cc  = t2 / 9;
    int i = tap / 3, j = tap - i * 3;
    int base = (oc * CIN_ + cc) * 9;
    float w0 = w[base + i * 3 + j];
    float w1 = w[base + (2 - j) * 3 + i];
    float w2 = w[base + (2 - i) * 3 + (2 - j)];
    float w3 = w[base + j * 3 + (2 - i)];
    float S, C;
    sincosf(wr[base + i * 3 + j], &S, &C);
    float* dst = tab + (size_t)idx * 12;
    dst[0]  = C;  dst[1]  = C;
    dst[2]  = S;  dst[3]  = S;
    dst[4]  = w0; dst[5]  = w0;
    dst[6]  = w1; dst[7]  = w1;
    dst[8]  = w2; dst[9]  = w2;
    dst[10] = w3; dst[11] = w3;
}

#define NC_    16                     // channels staged per barrier-pair
#define NG_    (CIN_ / NC_)           // 2 groups
#define ROWF_  68                     // floats per row = 34 pairs x 2
#define CLSTR_ (3 * ROWF_)            // 204 floats per staged channel
#define USED_  (NC_ * CLSTR_)         // 3264 slots per plane
#define PLANE_ 3268                   // plane stride (pad; 3268%32=4)
#define NRND_  7                      // staging rounds: ceil(3264/512)

__global__ __launch_bounds__(512, 4)
void orient_conv_kernel(const float* __restrict__ f,
                        const float* __restrict__ r0,
                        const float* __restrict__ r1,
                        const float* __restrict__ tab,
                        float* __restrict__ out)
{
    // planes: 0=f, PLANE_=r0, 2*PLANE_=r1. Within plane:
    // [cl(16)][row(3)][pairslot(68)] ; pairslot = c01*2+s holds col c01+32*s
    __shared__ float sm[3 * PLANE_];   // 39216 B

    const int tid   = threadIdx.x;
    const int oc    = tid & 31;
    const int pxg   = tid >> 5;            // 0..15
    const int p     = pxg << 1;            // even pair index 0..30
    const int bid   = blockIdx.x;          // 0..1023
    const int b     = bid >> 8;
    const int rem   = bid & 255;
    const int h     = rem >> 1;
    const int wbase = (rem & 1) << 6;      // 0 or 64

    // ---- staging descriptors: rounds 0..5 full, round 6 tid<192 ----
    int      goff[NRND_], sidx[NRND_];
    unsigned msk[NRND_];
#pragma unroll
    for (int k = 0; k < NRND_; ++k) {
        int s = tid + (k << 9);
        if (s < USED_) {
            int cl  = s / CLSTR_;
            int r2  = s - cl * CLSTR_;
            int row = r2 / ROWF_;
            int q2  = r2 - row * ROWF_;              // 0..67
            int col = (q2 >> 1) + ((q2 & 1) << 5);   // 0..65
            int gh = h + row - 1;
            int gw = wbase + col - 1;
            bool ok = ((unsigned)gh < (unsigned)H_) & ((unsigned)gw < (unsigned)W_);
            goff[k] = ok ? (cl * HW_ + gh * W_ + gw) : 0;
            msk[k]  = ok ? 0xFFFFFFFFu : 0u;
            sidx[k] = s;
        } else { goff[k] = 0; msk[k] = 0u; sidx[k] = USED_; }  // pad slot
    }
    const bool haveL = (tid + (NRND_ - 1) * 512) < USED_;   // tid < 192
    const int chanBase = b * (CIN_ * HW_);

    v2f acc[2][4];                     // [pair q][orient]; elems = px, px+32
#pragma unroll
    for (int q = 0; q < 2; ++q)
#pragma unroll
        for (int o = 0; o < 4; ++o) acc[q][o] = (v2f)(0.0f);

    // ---- prefetch group 0 ----
    float tF[NRND_], tA[NRND_], tB[NRND_];
    {
        const float* fb = f  + chanBase;
        const float* ab = r0 + chanBase;
        const float* bb = r1 + chanBase;
#pragma unroll
        for (int k = 0; k < NRND_ - 1; ++k) {
            tF[k] = fb[goff[k]]; tA[k] = ab[goff[k]]; tB[k] = bb[goff[k]];
        }
        if (haveL) {
            tF[NRND_-1] = fb[goff[NRND_-1]];
            tA[NRND_-1] = ab[goff[NRND_-1]];
            tB[NRND_-1] = bb[goff[NRND_-1]];
        }
    }

#pragma unroll 1
    for (int g = 0; g < NG_; ++g) {
        __syncthreads();   // all waves done reading LDS of group g-1
#pragma unroll
        for (int k = 0; k < NRND_ - 1; ++k) {
            sm[             sidx[k]] = __uint_as_float(__float_as_uint(tF[k]) & msk[k]);
            sm[PLANE_     + sidx[k]] = __uint_as_float(__float_as_uint(tA[k]) & msk[k]);
            sm[2 * PLANE_ + sidx[k]] = __uint_as_float(__float_as_uint(tB[k]) & msk[k]);
        }
        if (haveL) {
            sm[             sidx[NRND_-1]] = __uint_as_float(__float_as_uint(tF[NRND_-1]) & msk[NRND_-1]);
            sm[PLANE_     + sidx[NRND_-1]] = __uint_as_float(__float_as_uint(tA[NRND_-1]) & msk[NRND_-1]);
            sm[2 * PLANE_ + sidx[NRND_-1]] = __uint_as_float(__float_as_uint(tB[NRND_-1]) & msk[NRND_-1]);
        }
        __syncthreads();

        // ---- prefetch group g+1 (in flight during compute below) ----
        if (g + 1 < NG_) {
            const int gb = chanBase + (g + 1) * (NC_ * HW_);
            const float* fb = f  + gb;
            const float* ab = r0 + gb;
            const float* bb = r1 + gb;
#pragma unroll
            for (int k = 0; k < NRND_ - 1; ++k) {
                tF[k] = fb[goff[k]]; tA[k] = ab[goff[k]]; tB[k] = bb[goff[k]];
            }
            if (haveL) {
                tF[NRND_-1] = fb[goff[NRND_-1]];
                tA[NRND_-1] = ab[goff[NRND_-1]];
                tB[NRND_-1] = bb[goff[NRND_-1]];
            }
        }

        // ---- compute the NC_ staged channels ----
#pragma unroll 1
        for (int cl = 0; cl < NC_; ++cl) {
            const int cc = g * NC_ + cl;
            const float* wch = tab + (size_t)((cc * 9) * 32 + oc) * 12;
#pragma unroll
            for (int i = 0; i < 3; ++i) {
                const int bi = cl * CLSTR_ + i * ROWF_ + (p << 1);
                float4 fA = *reinterpret_cast<const float4*>(&sm[bi]);
                float4 fB = *reinterpret_cast<const float4*>(&sm[bi + 4]);
                float4 aA = *reinterpret_cast<const float4*>(&sm[PLANE_ + bi]);
                float4 aB = *reinterpret_cast<const float4*>(&sm[PLANE_ + bi + 4]);
                float4 bA = *reinterpret_cast<const float4*>(&sm[2 * PLANE_ + bi]);
                float4 bB = *reinterpret_cast<const float4*>(&sm[2 * PLANE_ + bi + 4]);
                v2f fP[4]  = {{fA.x, fA.y}, {fA.z, fA.w}, {fB.x, fB.y}, {fB.z, fB.w}};
                v2f aP[4]  = {{aA.x, aA.y}, {aA.z, aA.w}, {aB.x, aB.y}, {aB.z, aB.w}};
                v2f bP[4]  = {{bA.x, bA.y}, {bA.z, bA.w}, {bB.x, bB.y}, {bB.z, bB.w}};
#pragma unroll
                for (int j = 0; j < 3; ++j) {
                    const float* wp = wch + (i * 3 + j) * 384;   // 32 oc * 12
                    float4 Wcs = *reinterpret_cast<const float4*>(wp);      // C,C,S,S
                    float4 W01 = *reinterpret_cast<const float4*>(wp + 4);  // w0,w0,w1,w1
                    float4 W23 = *reinterpret_cast<const float4*>(wp + 8);  // w2,w2,w3,w3
                    v2f C2  = {Wcs.x, Wcs.y};
                    v2f S2  = {Wcs.z, Wcs.w};
                    v2f w02 = {W01.x, W01.y};
                    v2f w12 = {W01.z, W01.w};
                    v2f w22 = {W23.x, W23.y};
                    v2f w32 = {W23.z, W23.w};
#pragma unroll
                    for (int q = 0; q < 2; ++q) {
                        v2f fv  = fP[q + j];
                        v2f r0v = aP[q + j];
                        v2f r1v = bP[q + j];
                        v2f m1 = S2 * r1v;
                        v2f u  = __builtin_elementwise_fma(C2, r0v, m1);
                        v2f m2 = S2 * r0v;
                        v2f vv = __builtin_elementwise_fma(C2, r1v, -m2);
                        v2f g0 = __builtin_elementwise_max(u,  (v2f)(0.0f));
                        v2f g1 = __builtin_elementwise_max(vv, (v2f)(0.0f));
                        v2f t0 = fv * g0;
                        v2f t1 = fv * g1;
                        v2f t2 = __builtin_elementwise_fma(fv, -u,  t0);  // f*relu(-u)
                        v2f t3 = __builtin_elementwise_fma(fv, -vv, t1);  // f*relu(-vv)
                        acc[q][0] = __builtin_elementwise_fma(t0, w02, acc[q][0]);
                        acc[q][1] = __builtin_elementwise_fma(t1, w12, acc[q][1]);
                        acc[q][2] = __builtin_elementwise_fma(t2, w22, acc[q][2]);
                        acc[q][3] = __builtin_elementwise_fma(t3, w32, acc[q][3]);
                    }
                }
            }
        }
    }

    // ---- epilogue: max/argmax over orientations (first-max tie-break) ----
    const float cosv[4] = {1.0f, -4.37113883e-08f, -1.0f, 1.19248806e-08f};
    const float sinv[4] = {0.0f, 1.0f, -8.74227766e-08f, -1.0f};
#pragma unroll
    for (int q = 0; q < 2; ++q) {
#pragma unroll
        for (int k = 0; k < 2; ++k) {
            int wcol = wbase + p + q + (k << 5);
            float a0 = acc[q][0][k], a1 = acc[q][1][k];
            float a2 = acc[q][2][k], a3 = acc[q][3][k];
            float best = a0; int bi = 0;
            if (a1 > best) { best = a1; bi = 1; }
            if (a2 > best) { best = a2; bi = 2; }
            if (a3 > best) { best = a3; bi = 3; }
            size_t o = ((size_t)(b * COUT_ + oc) * H_ + h) * W_ + wcol;
            out[o]              = best;
            out[o + OUTSZ_]     = cosv[bi];
            out[o + 2 * OUTSZ_] = sinv[bi];
        }
    }
}

extern "C" void kernel_launch(void* const* d_in, const int* in_sizes, int n_in,
                              void* d_out, int out_size, void* d_ws, size_t ws_size,
                              hipStream_t stream)
{
    const float* f  = (const float*)d_in[0];
    const float* r0 = (const float*)d_in[1];
    const float* r1 = (const float*)d_in[2];
    const float* w  = (const float*)d_in[3];
    const float* wr = (const float*)d_in[4];
    float* out = (float*)d_out;
    float* tab = (float*)d_ws;    // 442368 B

    build_wtab<<<dim3(36), dim3(256), 0, stream>>>(w, wr, tab);
    orient_conv_kernel<<<dim3(B_ * H_ * 2), dim3(512), 0, stream>>>(
        f, r0, r1, tab, out);
}

// Round 13
// 303.776 us; speedup vs baseline: 1.0192x; 1.0192x over previous
//
#include <hip/hip_runtime.h>

// Orient_Conv: 3x3 orientation-gated conv, 4 orientations + per-pixel argmax.
// B=4, CIN=COUT=32, H=W=128, pad=1.
//
// Gate identity (C=cos(wr), S=sin(wr), r0=cos(th), r1=sin(th)):
//   u = C*r0+S*r1, vv = C*r1-S*r0
//   gates: o0=relu(u), o1=relu(vv), o2=relu(-u), o3=relu(-vv)
//   products: t0=f*relu(u), t1=f*relu(vv), t2=t0-f*u, t3=t1-f*vv
//   -> 14-slot packed core (VALU-slot floor ~108 us; v_pk = 2 slots).
// Rotated weights at tap (i,j): w0=w[i][j], w1=w[2-j][i], w2=w[2-i][2-j],
//   w3=w[j][2-i].
//
// R12 = R10 shell (239 us: NC=8, 4 staging rounds, 512 thr, VGPR 48 — the
// only proven no-spill pipeline) + R11's pre-duplicated weight table
// [cc][tap][oc][12] = {C,C,S,S,w0,w0,w1,w1,w2,w2,w3,w3}: 3 b128/tap, float4
// pairs alias directly to v2f operands -> zero splat movs (was 6/tap).
// R11 lesson: NC=16's 7-round prefetch state spills (compiler pins VGPR=64
// with a 2-arg launch_bounds; 25 MB scratch). NC=8 is the ceiling.

typedef float v2f __attribute__((ext_vector_type(2)));

#define B_    4
#define CIN_  32
#define COUT_ 32
#define H_    128
#define W_    128
#define HW_   (H_ * W_)
#define OUTSZ_ (B_ * COUT_ * H_ * W_)

// tab: [cc][tap][oc][12]; 9216 * 48 B = 442368 B
__global__ __launch_bounds__(256)
void build_wtab(const float* __restrict__ w, const float* __restrict__ wr,
                float* __restrict__ tab)
{
    int idx = blockIdx.x * 256 + threadIdx.x;   // ((cc*9+tap)<<5)|oc
    if (idx >= CIN_ * 9 * COUT_) return;        // 9216
    int oc  = idx & 31;
    int t2  = idx >> 5;
    int tap = t2 % 9;
    int cc  = t2 / 9;
    int i = tap / 3, j = tap - i * 3;
    int base = (oc * CIN_ + cc) * 9;
    float w0 = w[base + i * 3 + j];
    float w1 = w[base + (2 - j) * 3 + i];
    float w2 = w[base + (2 - i) * 3 + (2 - j)];
    float w3 = w[base + j * 3 + (2 - i)];
    float S, C;
    sincosf(wr[base + i * 3 + j], &S, &C);
    float* dst = tab + (size_t)idx * 12;
    dst[0]  = C;  dst[1]  = C;
    dst[2]  = S;  dst[3]  = S;
    dst[4]  = w0; dst[5]  = w0;
    dst[6]  = w1; dst[7]  = w1;
    dst[8]  = w2; dst[9]  = w2;
    dst[10] = w3; dst[11] = w3;
}

#define NC_    8                      // channels staged per barrier-pair
#define NG_    (CIN_ / NC_)           // 4 groups
#define ROWF_  68                     // floats per row = 34 pairs x 2
#define CLSTR_ (3 * ROWF_)            // 204 floats per staged channel
#define USED_  (NC_ * CLSTR_)         // 1632 slots per plane
#define PLANE_ 1636                   // plane stride (pad; 1636%32=4)

__global__ __launch_bounds__(512, 4)
void orient_conv_kernel(const float* __restrict__ f,
                        const float* __restrict__ r0,
                        const float* __restrict__ r1,
                        const float* __restrict__ tab,
                        float* __restrict__ out)
{
    // planes: 0=f, PLANE_=r0, 2*PLANE_=r1. Within plane:
    // [cl(8)][row(3)][pairslot(68)] ; pairslot = c01*2 + s holds col c01+32*s
    __shared__ float sm[3 * PLANE_];   // 19632 B

    const int tid   = threadIdx.x;
    const int oc    = tid & 31;
    const int pxg   = tid >> 5;            // 0..15
    const int p     = pxg << 1;            // even pair index 0..30
    const int bid   = blockIdx.x;          // 0..1023
    const int b     = bid >> 8;
    const int rem   = bid & 255;
    const int h     = rem >> 1;
    const int wbase = (rem & 1) << 6;      // 0 or 64

    // ---- staging descriptors: rounds 0..2 always valid, round 3 tid<96 ----
    int      goff[4], sidx[4];
    unsigned msk[4];
#pragma unroll
    for (int k = 0; k < 4; ++k) {
        int s = tid + (k << 9);
        if (s < USED_) {
            int cl  = s / CLSTR_;
            int r2  = s - cl * CLSTR_;
            int row = r2 / ROWF_;
            int q2  = r2 - row * ROWF_;     // 0..67
            int col = (q2 >> 1) + ((q2 & 1) << 5);   // c01 + 32*s -> 0..65
            int gh = h + row - 1;
            int gw = wbase + col - 1;
            bool ok = ((unsigned)gh < (unsigned)H_) & ((unsigned)gw < (unsigned)W_);
            goff[k] = ok ? (cl * HW_ + gh * W_ + gw) : 0;
            msk[k]  = ok ? 0xFFFFFFFFu : 0u;
            sidx[k] = s;
        } else { goff[k] = 0; msk[k] = 0u; sidx[k] = USED_; }  // pad slot
    }
    const bool have3 = (tid + 1536) < USED_;   // tid < 96
    const int chanBase = b * (CIN_ * HW_);

    v2f acc[2][4];                     // [pair q][orient]; elems = px, px+32
#pragma unroll
    for (int q = 0; q < 2; ++q)
#pragma unroll
        for (int o = 0; o < 4; ++o) acc[q][o] = (v2f)(0.0f);

    // ---- prefetch group 0 ----
    float tF[4], tA[4], tB[4];
    {
        const float* fb = f  + chanBase;
        const float* ab = r0 + chanBase;
        const float* bb = r1 + chanBase;
#pragma unroll
        for (int k = 0; k < 3; ++k) {
            tF[k] = fb[goff[k]]; tA[k] = ab[goff[k]]; tB[k] = bb[goff[k]];
        }
        if (have3) { tF[3] = fb[goff[3]]; tA[3] = ab[goff[3]]; tB[3] = bb[goff[3]]; }
    }

#pragma unroll 1
    for (int g = 0; g < NG_; ++g) {
        __syncthreads();   // all waves done reading LDS of group g-1
#pragma unroll
        for (int k = 0; k < 3; ++k) {
            sm[             sidx[k]] = __uint_as_float(__float_as_uint(tF[k]) & msk[k]);
            sm[PLANE_     + sidx[k]] = __uint_as_float(__float_as_uint(tA[k]) & msk[k]);
            sm[2 * PLANE_ + sidx[k]] = __uint_as_float(__float_as_uint(tB[k]) & msk[k]);
        }
        if (have3) {
            sm[             sidx[3]] = __uint_as_float(__float_as_uint(tF[3]) & msk[3]);
            sm[PLANE_     + sidx[3]] = __uint_as_float(__float_as_uint(tA[3]) & msk[3]);
            sm[2 * PLANE_ + sidx[3]] = __uint_as_float(__float_as_uint(tB[3]) & msk[3]);
        }
        __syncthreads();

        // ---- prefetch group g+1 (in flight during compute below) ----
        if (g + 1 < NG_) {
            const int gb = chanBase + (g + 1) * (NC_ * HW_);
            const float* fb = f  + gb;
            const float* ab = r0 + gb;
            const float* bb = r1 + gb;
#pragma unroll
            for (int k = 0; k < 3; ++k) {
                tF[k] = fb[goff[k]]; tA[k] = ab[goff[k]]; tB[k] = bb[goff[k]];
            }
            if (have3) { tF[3] = fb[goff[3]]; tA[3] = ab[goff[3]]; tB[3] = bb[goff[3]]; }
        }

        // ---- compute the NC_ staged channels ----
#pragma unroll 1
        for (int cl = 0; cl < NC_; ++cl) {
            const int cc = g * NC_ + cl;
            const float* wch = tab + (size_t)((cc * 9) * 32 + oc) * 12;
#pragma unroll
            for (int i = 0; i < 3; ++i) {
                const int bi = cl * CLSTR_ + i * ROWF_ + (p << 1);
                float4 fA = *reinterpret_cast<const float4*>(&sm[bi]);
                float4 fB = *reinterpret_cast<const float4*>(&sm[bi + 4]);
                float4 aA = *reinterpret_cast<const float4*>(&sm[PLANE_ + bi]);
                float4 aB = *reinterpret_cast<const float4*>(&sm[PLANE_ + bi + 4]);
                float4 bA = *reinterpret_cast<const float4*>(&sm[2 * PLANE_ + bi]);
                float4 bB = *reinterpret_cast<const float4*>(&sm[2 * PLANE_ + bi + 4]);
                v2f fP[4]  = {{fA.x, fA.y}, {fA.z, fA.w}, {fB.x, fB.y}, {fB.z, fB.w}};
                v2f aP[4]  = {{aA.x, aA.y}, {aA.z, aA.w}, {aB.x, aB.y}, {aB.z, aB.w}};
                v2f bP[4]  = {{bA.x, bA.y}, {bA.z, bA.w}, {bB.x, bB.y}, {bB.z, bB.w}};
#pragma unroll
                for (int j = 0; j < 3; ++j) {
                    const float* wp = wch + (i * 3 + j) * 384;   // 32 oc * 12
                    float4 Wcs = *reinterpret_cast<const float4*>(wp);      // C,C,S,S
                    float4 W01 = *reinterpret_cast<const float4*>(wp + 4);  // w0,w0,w1,w1
                    float4 W23 = *reinterpret_cast<const float4*>(wp + 8);  // w2,w2,w3,w3
                    v2f C2  = {Wcs.x, Wcs.y};
                    v2f S2  = {Wcs.z, Wcs.w};
                    v2f w02 = {W01.x, W01.y};
                    v2f w12 = {W01.z, W01.w};
                    v2f w22 = {W23.x, W23.y};
                    v2f w32 = {W23.z, W23.w};
#pragma unroll
                    for (int q = 0; q < 2; ++q) {
                        v2f fv  = fP[q + j];
                        v2f r0v = aP[q + j];
                        v2f r1v = bP[q + j];
                        v2f m1 = S2 * r1v;
                        v2f u  = __builtin_elementwise_fma(C2, r0v, m1);
                        v2f m2 = S2 * r0v;
                        v2f vv = __builtin_elementwise_fma(C2, r1v, -m2);
                        v2f g0 = __builtin_elementwise_max(u,  (v2f)(0.0f));
                        v2f g1 = __builtin_elementwise_max(vv, (v2f)(0.0f));
                        v2f t0 = fv * g0;
                        v2f t1 = fv * g1;
                        v2f t2 = __builtin_elementwise_fma(fv, -u,  t0);  // f*relu(-u)
                        v2f t3 = __builtin_elementwise_fma(fv, -vv, t1);  // f*relu(-vv)
                        acc[q][0] = __builtin_elementwise_fma(t0, w02, acc[q][0]);
                        acc[q][1] = __builtin_elementwise_fma(t1, w12, acc[q][1]);
                        acc[q][2] = __builtin_elementwise_fma(t2, w22, acc[q][2]);
                        acc[q][3] = __builtin_elementwise_fma(t3, w32, acc[q][3]);
                    }
                }
            }
        }
    }

    // ---- epilogue: max/argmax over orientations (first-max tie-break) ----
    const float cosv[4] = {1.0f, -4.37113883e-08f, -1.0f, 1.19248806e-08f};
    const float sinv[4] = {0.0f, 1.0f, -8.74227766e-08f, -1.0f};
#pragma unroll
    for (int q = 0; q < 2; ++q) {
#pragma unroll
        for (int k = 0; k < 2; ++k) {
            int wcol = wbase + p + q + (k << 5);
            float a0 = acc[q][0][k], a1 = acc[q][1][k];
            float a2 = acc[q][2][k], a3 = acc[q][3][k];
            float best = a0; int bi = 0;
            if (a1 > best) { best = a1; bi = 1; }
            if (a2 > best) { best = a2; bi = 2; }
            if (a3 > best) { best = a3; bi = 3; }
            size_t o = ((size_t)(b * COUT_ + oc) * H_ + h) * W_ + wcol;
            out[o]              = best;
            out[o + OUTSZ_]     = cosv[bi];
            out[o + 2 * OUTSZ_] = sinv[bi];
        }
    }
}

extern "C" void kernel_launch(void* const* d_in, const int* in_sizes, int n_in,
                              void* d_out, int out_size, void* d_ws, size_t ws_size,
                              hipStream_t stream)
{
    const float* f  = (const float*)d_in[0];
    const float* r0 = (const float*)d_in[1];
    const float* r1 = (const float*)d_in[2];
    const float* w  = (const float*)d_in[3];
    const float* wr = (const float*)d_in[4];
    float* out = (float*)d_out;
    float* tab = (float*)d_ws;    // 442368 B

    build_wtab<<<dim3(36), dim3(256), 0, stream>>>(w, wr, tab);
    orient_conv_kernel<<<dim3(B_ * H_ * 2), dim3(512), 0, stream>>>(
        f, r0, r1, tab, out);
}

// Round 14
// 288.904 us; speedup vs baseline: 1.0717x; 1.0515x over previous
//
#include <hip/hip_runtime.h>

// Orient_Conv: 3x3 orientation-gated conv, 4 orientations + per-pixel argmax.
// B=4, CIN=COUT=32, H=W=128, pad=1.
//
// Gate identity (C=cos(wr), S=sin(wr), r0=cos(th), r1=sin(th)):
//   u = C*r0+S*r1, vv = C*r1-S*r0
//   gates: o0=relu(u), o1=relu(vv), o2=relu(-u), o3=relu(-vv)
//   products: t0=f*relu(u), t1=f*relu(vv), t2=t0-f*u, t3=t1-f*vv
//   -> 14-slot packed core (VALU-slot floor ~108 us; v_pk = 2 slots).
// Rotated weights at tap (i,j): w0=w[i][j], w1=w[2-j][i], w2=w[2-i][2-j],
//   w3=w[j][2-i].
//
// R13 = R10 (239 us champion: NC=8, interleaved-pair LDS, [cc][tap][oc][8]
// weight table — R12 proved the dedup table is a wash since v_pk op_sel
// broadcasts scalars for free) + LDS DOUBLE-BUFFER: compute group g from
// buf[g&1] while writing prefetched group g+1 into buf[(g+1)&1]; ONE
// barrier per group (was 2). Staging writes leave the critical path and the
// vmcnt drain lands after ~10k cyc of compute. R10 idle was 89 us of
// barrier convoy; this attacks it directly. LDS 39.3 KB -> 4 blocks/CU.

typedef float v2f __attribute__((ext_vector_type(2)));

#define B_    4
#define CIN_  32
#define COUT_ 32
#define H_    128
#define W_    128
#define HW_   (H_ * W_)
#define OUTSZ_ (B_ * COUT_ * H_ * W_)

// tab layout: [cc][tap][oc][8] = {C,S,w0,w1,w2,w3,0,0}; 294912 B
__global__ __launch_bounds__(256)
void build_wtab(const float* __restrict__ w, const float* __restrict__ wr,
                float* __restrict__ tab)
{
    int idx = blockIdx.x * 256 + threadIdx.x;   // ((cc*9+tap)<<5)|oc
    if (idx >= CIN_ * 9 * COUT_) return;        // 9216
    int oc  = idx & 31;
    int t2  = idx >> 5;
    int tap = t2 % 9;
    int cc  = t2 / 9;
    int i = tap / 3, j = tap - i * 3;
    int base = (oc * CIN_ + cc) * 9;
    float w0 = w[base + i * 3 + j];
    float w1 = w[base + (2 - j) * 3 + i];
    float w2 = w[base + (2 - i) * 3 + (2 - j)];
    float w3 = w[base + j * 3 + (2 - i)];
    float S, C;
    sincosf(wr[base + i * 3 + j], &S, &C);
    float* dst = tab + (size_t)idx * 8;
    dst[0] = C;  dst[1] = S;
    dst[2] = w0; dst[3] = w1;
    dst[4] = w2; dst[5] = w3;
    dst[6] = 0.0f; dst[7] = 0.0f;
}

#define NC_    8                      // channels staged per group
#define NG_    (CIN_ / NC_)           // 4 groups
#define ROWF_  68                     // floats per row = 34 pairs x 2
#define CLSTR_ (3 * ROWF_)            // 204 floats per staged channel
#define USED_  (NC_ * CLSTR_)         // 1632 slots per plane
#define PLANE_ 1636                   // plane stride (pad; 1636%32=4)
#define BUF_   (3 * PLANE_)           // one buffer = 3 planes

__global__ __launch_bounds__(512, 4)
void orient_conv_kernel(const float* __restrict__ f,
                        const float* __restrict__ r0,
                        const float* __restrict__ r1,
                        const float* __restrict__ tab,
                        float* __restrict__ out)
{
    // two buffers x three planes (0=f, PLANE_=r0, 2*PLANE_=r1). Within plane:
    // [cl(8)][row(3)][pairslot(68)] ; pairslot = c01*2 + s holds col c01+32*s
    __shared__ float sm[2 * BUF_];     // 39264 B

    const int tid   = threadIdx.x;
    const int oc    = tid & 31;
    const int pxg   = tid >> 5;            // 0..15
    const int p     = pxg << 1;            // even pair index 0..30
    const int bid   = blockIdx.x;          // 0..1023
    const int b     = bid >> 8;
    const int rem   = bid & 255;
    const int h     = rem >> 1;
    const int wbase = (rem & 1) << 6;      // 0 or 64

    // ---- staging descriptors: rounds 0..2 always valid, round 3 tid<96 ----
    int      goff[4], sidx[4];
    unsigned msk[4];
#pragma unroll
    for (int k = 0; k < 4; ++k) {
        int s = tid + (k << 9);
        if (s < USED_) {
            int cl  = s / CLSTR_;
            int r2  = s - cl * CLSTR_;
            int row = r2 / ROWF_;
            int q2  = r2 - row * ROWF_;     // 0..67
            int col = (q2 >> 1) + ((q2 & 1) << 5);   // c01 + 32*s -> 0..65
            int gh = h + row - 1;
            int gw = wbase + col - 1;
            bool ok = ((unsigned)gh < (unsigned)H_) & ((unsigned)gw < (unsigned)W_);
            goff[k] = ok ? (cl * HW_ + gh * W_ + gw) : 0;
            msk[k]  = ok ? 0xFFFFFFFFu : 0u;
            sidx[k] = s;
        } else { goff[k] = 0; msk[k] = 0u; sidx[k] = USED_; }  // pad slot
    }
    const bool have3 = (tid + 1536) < USED_;   // tid < 96
    const int chanBase = b * (CIN_ * HW_);

    v2f acc[2][4];                     // [pair q][orient]; elems = px, px+32
#pragma unroll
    for (int q = 0; q < 2; ++q)
#pragma unroll
        for (int o = 0; o < 4; ++o) acc[q][o] = (v2f)(0.0f);

    // ---- prologue: load group 0, write buf0, one barrier ----
    float tF[4], tA[4], tB[4];
    {
        const float* fb = f  + chanBase;
        const float* ab = r0 + chanBase;
        const float* bb = r1 + chanBase;
#pragma unroll
        for (int k = 0; k < 3; ++k) {
            tF[k] = fb[goff[k]]; tA[k] = ab[goff[k]]; tB[k] = bb[goff[k]];
        }
        if (have3) { tF[3] = fb[goff[3]]; tA[3] = ab[goff[3]]; tB[3] = bb[goff[3]]; }
    }
    {
        float* bw = sm;    // buffer 0
#pragma unroll
        for (int k = 0; k < 3; ++k) {
            bw[             sidx[k]] = __uint_as_float(__float_as_uint(tF[k]) & msk[k]);
            bw[PLANE_     + sidx[k]] = __uint_as_float(__float_as_uint(tA[k]) & msk[k]);
            bw[2 * PLANE_ + sidx[k]] = __uint_as_float(__float_as_uint(tB[k]) & msk[k]);
        }
        if (have3) {
            bw[             sidx[3]] = __uint_as_float(__float_as_uint(tF[3]) & msk[3]);
            bw[PLANE_     + sidx[3]] = __uint_as_float(__float_as_uint(tA[3]) & msk[3]);
            bw[2 * PLANE_ + sidx[3]] = __uint_as_float(__float_as_uint(tB[3]) & msk[3]);
        }
    }
    __syncthreads();

#pragma unroll 1
    for (int g = 0; g < NG_; ++g) {
        // ---- issue global prefetch for group g+1 (no wait) ----
        if (g + 1 < NG_) {
            const int gb = chanBase + (g + 1) * (NC_ * HW_);
            const float* fb = f  + gb;
            const float* ab = r0 + gb;
            const float* bb = r1 + gb;
#pragma unroll
            for (int k = 0; k < 3; ++k) {
                tF[k] = fb[goff[k]]; tA[k] = ab[goff[k]]; tB[k] = bb[goff[k]];
            }
            if (have3) { tF[3] = fb[goff[3]]; tA[3] = ab[goff[3]]; tB[3] = bb[goff[3]]; }
        }

        // ---- compute the NC_ staged channels from buf[g&1] ----
        const float* br = sm + (g & 1) * BUF_;
#pragma unroll 1
        for (int cl = 0; cl < NC_; ++cl) {
            const int cc = g * NC_ + cl;
            // imm-offset anchors (taps 2 and 6): all 18 weight loads within
            // signed-13-bit global imm offsets
            const float* wb0 = tab + (size_t)(((cc * 9 + 2) << 5) | oc) * 8;
            const float* wb1 = wb0 + 4 * 256;
#pragma unroll
            for (int i = 0; i < 3; ++i) {
                const int bi = cl * CLSTR_ + i * ROWF_ + (p << 1);
                float4 fA = *reinterpret_cast<const float4*>(&br[bi]);
                float4 fB = *reinterpret_cast<const float4*>(&br[bi + 4]);
                float4 aA = *reinterpret_cast<const float4*>(&br[PLANE_ + bi]);
                float4 aB = *reinterpret_cast<const float4*>(&br[PLANE_ + bi + 4]);
                float4 bA = *reinterpret_cast<const float4*>(&br[2 * PLANE_ + bi]);
                float4 bB = *reinterpret_cast<const float4*>(&br[2 * PLANE_ + bi + 4]);
                v2f fP[4]  = {{fA.x, fA.y}, {fA.z, fA.w}, {fB.x, fB.y}, {fB.z, fB.w}};
                v2f aP[4]  = {{aA.x, aA.y}, {aA.z, aA.w}, {aB.x, aB.y}, {aB.z, aB.w}};
                v2f bP[4]  = {{bA.x, bA.y}, {bA.z, bA.w}, {bB.x, bB.y}, {bB.z, bB.w}};
#pragma unroll
                for (int j = 0; j < 3; ++j) {
                    const int tap = i * 3 + j;
                    const float* wp = (tap < 5) ? (wb0 + (tap - 2) * 256)
                                                : (wb1 + (tap - 6) * 256);
                    float4 W4 = *reinterpret_cast<const float4*>(wp);
                    float2 W2 = *reinterpret_cast<const float2*>(wp + 4);
                    v2f C2  = {W4.x, W4.x};
                    v2f S2  = {W4.y, W4.y};
                    v2f w02 = {W4.z, W4.z};
                    v2f w12 = {W4.w, W4.w};
                    v2f w22 = {W2.x, W2.x};
                    v2f w32 = {W2.y, W2.y};
#pragma unroll
                    for (int q = 0; q < 2; ++q) {
                        v2f fv  = fP[q + j];
                        v2f r0v = aP[q + j];
                        v2f r1v = bP[q + j];
                        v2f m1 = S2 * r1v;
                        v2f u  = __builtin_elementwise_fma(C2, r0v, m1);
                        v2f m2 = S2 * r0v;
                        v2f vv = __builtin_elementwise_fma(C2, r1v, -m2);
                        v2f g0 = __builtin_elementwise_max(u,  (v2f)(0.0f));
                        v2f g1 = __builtin_elementwise_max(vv, (v2f)(0.0f));
                        v2f t0 = fv * g0;
                        v2f t1 = fv * g1;
                        v2f t2 = __builtin_elementwise_fma(fv, -u,  t0);  // f*relu(-u)
                        v2f t3 = __builtin_elementwise_fma(fv, -vv, t1);  // f*relu(-vv)
                        acc[q][0] = __builtin_elementwise_fma(t0, w02, acc[q][0]);
                        acc[q][1] = __builtin_elementwise_fma(t1, w12, acc[q][1]);
                        acc[q][2] = __builtin_elementwise_fma(t2, w22, acc[q][2]);
                        acc[q][3] = __builtin_elementwise_fma(t3, w32, acc[q][3]);
                    }
                }
            }
        }

        // ---- write group g+1 into buf[(g+1)&1] (readers are in buf[g&1]),
        //      then ONE barrier: publishes buf[(g+1)&1] AND retires buf[g&1]
        if (g + 1 < NG_) {
            float* bw = sm + ((g + 1) & 1) * BUF_;
#pragma unroll
            for (int k = 0; k < 3; ++k) {
                bw[             sidx[k]] = __uint_as_float(__float_as_uint(tF[k]) & msk[k]);
                bw[PLANE_     + sidx[k]] = __uint_as_float(__float_as_uint(tA[k]) & msk[k]);
                bw[2 * PLANE_ + sidx[k]] = __uint_as_float(__float_as_uint(tB[k]) & msk[k]);
            }
            if (have3) {
                bw[             sidx[3]] = __uint_as_float(__float_as_uint(tF[3]) & msk[3]);
                bw[PLANE_     + sidx[3]] = __uint_as_float(__float_as_uint(tA[3]) & msk[3]);
                bw[2 * PLANE_ + sidx[3]] = __uint_as_float(__float_as_uint(tB[3]) & msk[3]);
            }
            __syncthreads();
        }
    }

    // ---- epilogue: max/argmax over orientations (first-max tie-break) ----
    const float cosv[4] = {1.0f, -4.37113883e-08f, -1.0f, 1.19248806e-08f};
    const float sinv[4] = {0.0f, 1.0f, -8.74227766e-08f, -1.0f};
#pragma unroll
    for (int q = 0; q < 2; ++q) {
#pragma unroll
        for (int k = 0; k < 2; ++k) {
            int wcol = wbase + p + q + (k << 5);
            float a0 = acc[q][0][k], a1 = acc[q][1][k];
            float a2 = acc[q][2][k], a3 = acc[q][3][k];
            float best = a0; int bi = 0;
            if (a1 > best) { best = a1; bi = 1; }
            if (a2 > best) { best = a2; bi = 2; }
            if (a3 > best) { best = a3; bi = 3; }
            size_t o = ((size_t)(b * COUT_ + oc) * H_ + h) * W_ + wcol;
            out[o]              = best;
            out[o + OUTSZ_]     = cosv[bi];
            out[o + 2 * OUTSZ_] = sinv[bi];
        }
    }
}

extern "C" void kernel_launch(void* const* d_in, const int* in_sizes, int n_in,
                              void* d_out, int out_size, void* d_ws, size_t ws_size,
                              hipStream_t stream)
{
    const float* f  = (const float*)d_in[0];
    const float* r0 = (const float*)d_in[1];
    const float* r1 = (const float*)d_in[2];
    const float* w  = (const float*)d_in[3];
    const float* wr = (const float*)d_in[4];
    float* out = (float*)d_out;
    float* tab = (float*)d_ws;    // 294912 B

    build_wtab<<<dim3(36), dim3(256), 0, stream>>>(w, wr, tab);
    orient_conv_kernel<<<dim3(B_ * H_ * 2), dim3(512), 0, stream>>>(
        f, r0, r1, tab, out);
}